// Round 7
// baseline (272.277 us; speedup 1.0000x reference)
//
#include <hip/hip_runtime.h>

typedef __bf16 bf16;
typedef __attribute__((ext_vector_type(8))) __bf16 bf16x8;
typedef __attribute__((ext_vector_type(4))) float f32x4;
typedef __attribute__((ext_vector_type(4))) unsigned short u16x4;

#define D_MODEL 1024
#define SEQ     2048
#define NB      4
#define NH      16
#define DK      64
#define MROWS   (NB * SEQ)   // 8192

#define MFMA_BF16 __builtin_amdgcn_mfma_f32_16x16x32_bf16
#define EXP2F(x) __builtin_amdgcn_exp2f(x)
#define QSCALE 0.18033688011112042f   // 0.125 * log2(e)

__device__ __forceinline__ bf16 f2b(float f) {
    union { float f; unsigned u; } c; c.f = f;
    unsigned r = (c.u + 0x7fffu + ((c.u >> 16) & 1u)) >> 16;
    union { unsigned short s; bf16 b; } o; o.s = (unsigned short)r;
    return o.b;
}
__device__ __forceinline__ unsigned short f2u(float f) {
    union { float f; unsigned u; } c; c.f = f;
    return (unsigned short)((c.u + 0x7fffu + ((c.u >> 16) & 1u)) >> 16);
}
__device__ __forceinline__ unsigned fbits(float f) {
    union { float f; unsigned u; } c; c.f = f; return c.u;
}
// pack two fp32 -> two bf16 (truncation) in one v_perm_b32
__device__ __forceinline__ unsigned pack2(float lo, float hi) {
    return __builtin_amdgcn_perm(fbits(hi), fbits(lo), 0x07060302u);
}

// ---------------------------------------------------------------- prep (fused)
__global__ void prep_kernel(const float* __restrict__ X,
                            const float* __restrict__ Wq, const float* __restrict__ Wk,
                            const float* __restrict__ Wv, const float* __restrict__ Wo,
                            bf16* __restrict__ Xb, bf16* __restrict__ WqkT,
                            bf16* __restrict__ WvT, bf16* __restrict__ WoT) {
    __shared__ float tile[32][33];
    const int bid = blockIdx.x;
    if (bid < 8192) {
        int i = bid * 256 + threadIdx.x;
        float4 v = ((const float4*)X)[i];
        u16x4 o; o[0] = f2u(v.x); o[1] = f2u(v.y); o[2] = f2u(v.z); o[3] = f2u(v.w);
        ((u16x4*)Xb)[i] = o;
    } else {
        int r = bid - 8192;
        int w = r >> 10, tl = r & 1023;
        const float* src = (w == 0) ? Wq : (w == 1) ? Wk : (w == 2) ? Wv : Wo;
        bf16* dst = (w == 0) ? WqkT : (w == 1) ? WqkT + (size_t)1024 * 1024
                  : (w == 2) ? WvT : WoT;
        const int n0 = (tl & 31) * 32, k0 = (tl >> 5) * 32;
        const int tx = threadIdx.x & 31, ty = threadIdx.x >> 5;
#pragma unroll
        for (int i = 0; i < 4; i++)
            tile[ty + i * 8][tx] = src[(size_t)(k0 + ty + i * 8) * 1024 + n0 + tx];
        __syncthreads();
#pragma unroll
        for (int i = 0; i < 4; i++)
            dst[(size_t)(n0 + ty + i * 8) * 1024 + k0 + tx] = f2b(tile[tx][ty + i * 8]);
    }
}

// ---------------------------------------------------------------- GEMM
// 128x128 tile, BK=64, source-side XOR swizzle. 1D grid, XCD-pinned columns:
// each XCD (bid&7) owns a fixed set of B-column strips so B stays in its L2.
// MODE 0: fp32 out [m][n] (512 blocks: col=bid&7, row=bid>>3)
// MODE 1: fused QK (1024 blocks: col=(bid&7)*2+(s&1), row=s>>1)
// MODE 2: V -> bf16 [bh][dk][s] (512 blocks)
template <int MODE>
__global__ __launch_bounds__(256) void gemm128(const bf16* __restrict__ A,
                                               const bf16* __restrict__ Bt,
                                               void* __restrict__ out) {
    __shared__ __align__(16) bf16 lA[128 * 64];
    __shared__ __align__(16) bf16 lB[128 * 64];

    const int t = threadIdx.x;
    const int wid = t >> 6, lane = t & 63;
    const int ln = lane & 15, qd = lane >> 4;
    const int wm = wid >> 1, wn = wid & 1;

    const int bid = blockIdx.x;
    int rowb, colb;
    if (MODE == 1) {
        int s = bid >> 3;
        colb = (bid & 7) * 2 + (s & 1);
        rowb = s >> 1;
    } else {
        colb = bid & 7;
        rowb = bid >> 3;
    }
    const int row0 = rowb * 128, col0 = colb * 128;

    const int srow = t >> 3;
    const int schunk = (t & 7) ^ (srow & 7);
    const bf16* ga = A  + (size_t)(row0 + srow) * 1024 + schunk * 8;
    const bf16* gb = Bt + (size_t)(col0 + srow) * 1024 + schunk * 8;
    const int swk = ln & 7;

    f32x4 acc[4][4];
#pragma unroll
    for (int i = 0; i < 4; i++)
#pragma unroll
        for (int j = 0; j < 4; j++) acc[i][j] = (f32x4){0.f, 0.f, 0.f, 0.f};

    for (int kb = 0; kb < 1024; kb += 64) {
#pragma unroll
        for (int c = 0; c < 4; c++) {
            __builtin_amdgcn_global_load_lds(
                (const __attribute__((address_space(1))) void*)(ga + kb + (size_t)c * 32 * 1024),
                (__attribute__((address_space(3))) void*)(&lA[t * 8 + c * 2048]), 16, 0, 0);
            __builtin_amdgcn_global_load_lds(
                (const __attribute__((address_space(1))) void*)(gb + kb + (size_t)c * 32 * 1024),
                (__attribute__((address_space(3))) void*)(&lB[t * 8 + c * 2048]), 16, 0, 0);
        }
        __syncthreads();

#pragma unroll
        for (int ks = 0; ks < 2; ks++) {
            bf16x8 af[4], bfr[4];
#pragma unroll
            for (int i = 0; i < 4; i++)
                af[i] = *(const bf16x8*)&lA[(wm * 64 + i * 16 + ln) * 64
                                            + ((ks * 4 + qd) ^ swk) * 8];
#pragma unroll
            for (int j = 0; j < 4; j++)
                bfr[j] = *(const bf16x8*)&lB[(wn * 64 + j * 16 + ln) * 64
                                             + ((ks * 4 + qd) ^ swk) * 8];
#pragma unroll
            for (int i = 0; i < 4; i++)
#pragma unroll
                for (int j = 0; j < 4; j++) {
                    if (MODE == 2)
                        acc[i][j] = MFMA_BF16(af[i], bfr[j], acc[i][j], 0, 0, 0);
                    else
                        acc[i][j] = MFMA_BF16(bfr[j], af[i], acc[i][j], 0, 0, 0);
                }
        }
        __syncthreads();
    }

#pragma unroll
    for (int i = 0; i < 4; i++)
#pragma unroll
        for (int j = 0; j < 4; j++) {
            if (MODE == 0) {
                int m  = row0 + wm * 64 + i * 16 + ln;
                int n0 = col0 + wn * 64 + j * 16 + qd * 4;
                *(f32x4*)&((float*)out)[(size_t)m * 1024 + n0] = acc[i][j];
            } else if (MODE == 1) {
                int m  = row0 + wm * 64 + i * 16 + ln;
                int n0 = col0 + wn * 64 + j * 16 + qd * 4;
                float scale = (n0 < 1024) ? QSCALE : 1.0f;
                int b = m >> 11, s = m & 2047;
                int h = (n0 & 1023) >> 6, d0 = n0 & 63;
                size_t addr = (((size_t)(b * NH + h) * SEQ + s) * DK + d0)
                              + (size_t)(n0 >> 10) * 8388608;
                u16x4 w;
#pragma unroll
                for (int r = 0; r < 4; r++) w[r] = f2u(acc[i][j][r] * scale);
                *(u16x4*)&((bf16*)out)[addr] = w;
            } else {
                int m0 = row0 + wm * 64 + i * 16 + qd * 4;
                int n  = col0 + wn * 64 + j * 16 + ln;
                int b = m0 >> 11, s0 = m0 & 2047;
                int h = n >> 6, d = n & 63;
                size_t addr = ((size_t)(b * NH + h) * DK + d) * SEQ + s0;
                u16x4 w;
#pragma unroll
                for (int r = 0; r < 4; r++) w[r] = f2u(acc[i][j][r]);
                *(u16x4*)&((bf16*)out)[addr] = w;
            }
        }
}

// ---------------------------------------------------------------- attention
// Block = 4 waves = one bh, one PAIR of 128-query tiles (gA=p, gB=15-p): every
// block does exactly 36 uniform 64-key steps. Each wave owns 32 queries (two
// 16-row frags) -> K/V LDS fragment reads are shared across 2x the work, and
// per-step VALU overhead is halved per unit work. K/V double-buffered via
// global_load_lds (source-side XOR swizzle). Fixed-m softmax; diagonal mask on
// the (per-frag) single wave-uniform 16x16 block; P v_perm-truncated into
// per-wave-per-frag swizzled LDS. 48 KB LDS -> 2 blocks/CU (512 blocks total,
// all co-resident).
__global__ __launch_bounds__(256) void attn_kernel(const bf16* __restrict__ Q,
                                                   const bf16* __restrict__ K,
                                                   const bf16* __restrict__ Vt,
                                                   bf16* __restrict__ attn_out) {
    __shared__ __align__(16) bf16 kbuf[2][64 * 64];
    __shared__ __align__(16) bf16 vbuf[2][64 * 64];
    __shared__ __align__(16) bf16 plds[4][2][16 * 64];

    const int t = threadIdx.x;
    const int wid = t >> 6, lane = t & 63;
    const int ln = lane & 15, qd = lane >> 4;

    const int bid = blockIdx.x;                        // 512 blocks
    const int bh   = ((bid >> 6) << 3) | (bid & 7);    // XCD swizzle: bh%8 = XCD
    const int pair = (bid >> 3) & 7;
    const int gA = pair, gB = 15 - pair;               // 128-query tiles
    const int ntA = 2 * gA + 2, ntT = 36;              // uniform 36 steps

    const bf16* Qh = Q  + (size_t)bh * SEQ * DK;
    const bf16* Kh = K  + (size_t)bh * SEQ * DK;
    const bf16* Vh = Vt + (size_t)bh * DK * SEQ;
    bf16* pw0 = &plds[wid][0][0];
    bf16* pw1 = &plds[wid][1][0];

    const int srow = t >> 3;
    const int schunk = (t & 7) ^ (srow & 7);
    const bf16* kgp = Kh + (size_t)srow * DK + schunk * 8;
    const bf16* vgp = Vh + (size_t)srow * SEQ + schunk * 8;
    const int swk = ln & 7;

    f32x4 o0[4], o1[4];
    float l0, l1;
    int qw0;
    bf16x8 qf00, qf01, qf10, qf11;   // [frag][dk-half]

    auto stage = [&](int kb, int buf) {
#pragma unroll
        for (int c = 0; c < 2; c++) {
            __builtin_amdgcn_global_load_lds(
                (const __attribute__((address_space(1))) void*)(kgp + (size_t)(kb + c * 32) * DK),
                (__attribute__((address_space(3))) void*)(&kbuf[buf][t * 8 + c * 2048]), 16, 0, 0);
            __builtin_amdgcn_global_load_lds(
                (const __attribute__((address_space(1))) void*)(vgp + (size_t)c * 32 * SEQ + kb),
                (__attribute__((address_space(3))) void*)(&vbuf[buf][t * 8 + c * 2048]), 16, 0, 0);
        }
    };
    auto initGroup = [&](int g) {
        qw0 = g * 128 + wid * 32;
        qf00 = *(const bf16x8*)(Qh + (size_t)(qw0 + ln) * DK + qd * 8);
        qf01 = *(const bf16x8*)(Qh + (size_t)(qw0 + ln) * DK + 32 + qd * 8);
        qf10 = *(const bf16x8*)(Qh + (size_t)(qw0 + 16 + ln) * DK + qd * 8);
        qf11 = *(const bf16x8*)(Qh + (size_t)(qw0 + 16 + ln) * DK + 32 + qd * 8);
#pragma unroll
        for (int c = 0; c < 4; c++) {
            o0[c] = (f32x4){0.f, 0.f, 0.f, 0.f};
            o1[c] = (f32x4){0.f, 0.f, 0.f, 0.f};
        }
        l0 = 0.f; l1 = 0.f;
    };
    const int b = bh >> 4, h = bh & 15;
    auto finalize = [&]() {
#pragma unroll
        for (int f = 0; f < 2; f++) {
            float ll = f ? l1 : l0;
            ll += __shfl_xor(ll, 16);
            ll += __shfl_xor(ll, 32);
            float inv = 1.0f / ll;
            size_t orow = ((size_t)(b * SEQ + qw0 + f * 16 + ln)) * D_MODEL + h * DK;
#pragma unroll
            for (int c = 0; c < 4; c++) {
                u16x4 w;
#pragma unroll
                for (int r = 0; r < 4; r++)
                    w[r] = f2u((f ? o1[c][r] : o0[c][r]) * inv);
                *(u16x4*)&attn_out[orow + c * 16 + qd * 4] = w;
            }
        }
    };

    stage(0, 0);
    initGroup(gA);
    int cur = 0;

    for (int i = 0; i < ntT; i++) {
        __syncthreads();
        int nx = i + 1;
        if (nx < ntT) {
            int kbn = ((nx < ntA) ? nx : nx - ntA) * 64;
            stage(kbn, cur ^ 1);
        }
        const int kb = ((i < ntA) ? i : i - ntA) * 64;
        const int nkk1 = min(4, max(0, ((qw0 + 31 - kb) >> 4) + 1));
        const int nkk0 = min(4, max(0, ((qw0 + 15 - kb) >> 4) + 1));

        if (nkk1 > 0) {
            // scores for both frags; K frag loaded once
            f32x4 st0[4], st1[4];
#pragma unroll
            for (int kk = 0; kk < 4; kk++)
                if (kk < nkk1) {
                    const bf16* base = &kbuf[cur][(kk * 16 + ln) * 64];
                    bf16x8 kf0 = *(const bf16x8*)(base + ((qd    ) ^ swk) * 8);
                    bf16x8 kf1 = *(const bf16x8*)(base + ((qd + 4) ^ swk) * 8);
                    f32x4 z = (f32x4){0.f, 0.f, 0.f, 0.f};
                    st1[kk] = MFMA_BF16(kf0, qf10, z, 0, 0, 0);
                    st1[kk] = MFMA_BF16(kf1, qf11, st1[kk], 0, 0, 0);
                    if (kk < nkk0) {
                        st0[kk] = MFMA_BF16(kf0, qf00, z, 0, 0, 0);
                        st0[kk] = MFMA_BF16(kf1, qf01, st0[kk], 0, 0, 0);
                    }
                }

            float ps0 = 0.f, ps1 = 0.f;
#pragma unroll
            for (int kk = 0; kk < 4; kk++) {
                // frag 1
                unsigned a0 = 0, a1 = 0;
                if (kk < nkk1) {
                    f32x4 s = st1[kk];
                    if (kb + kk * 16 == qw0 + 16) {
#pragma unroll
                        for (int r = 0; r < 4; r++)
                            if (qd * 4 + r > ln) s[r] = -INFINITY;
                    }
                    float p0 = EXP2F(s[0]), p1 = EXP2F(s[1]);
                    float p2 = EXP2F(s[2]), p3 = EXP2F(s[3]);
                    ps1 += (p0 + p1) + (p2 + p3);
                    a0 = pack2(p0, p1); a1 = pack2(p2, p3);
                }
                int cw = (2 * kk + (qd >> 1)) ^ swk;
                *(uint2*)&pw1[ln * 64 + cw * 8 + (qd & 1) * 4] = make_uint2(a0, a1);
                // frag 0
                unsigned b0 = 0, b1 = 0;
                if (kk < nkk0) {
                    f32x4 s = st0[kk];
                    if (kb + kk * 16 == qw0) {
#pragma unroll
                        for (int r = 0; r < 4; r++)
                            if (qd * 4 + r > ln) s[r] = -INFINITY;
                    }
                    float p0 = EXP2F(s[0]), p1 = EXP2F(s[1]);
                    float p2 = EXP2F(s[2]), p3 = EXP2F(s[3]);
                    ps0 += (p0 + p1) + (p2 + p3);
                    b0 = pack2(p0, p1); b1 = pack2(p2, p3);
                }
                *(uint2*)&pw0[ln * 64 + cw * 8 + (qd & 1) * 4] = make_uint2(b0, b1);
            }
            l1 += ps1; l0 += ps0;

            asm volatile("s_waitcnt lgkmcnt(0)" ::: "memory");

#pragma unroll
            for (int half = 0; half < 2; half++)
                if (half == 0 || nkk1 > 2) {
                    const int pc = ((half * 4 + qd) ^ swk) * 8;
                    bf16x8 pa1 = *(const bf16x8*)&pw1[ln * 64 + pc];
                    bf16x8 pa0 = *(const bf16x8*)&pw0[ln * 64 + pc];
                    bool f0act = (half == 0) ? (nkk0 > 0) : (nkk0 > 2);
#pragma unroll
                    for (int c = 0; c < 4; c++) {
                        bf16x8 vf = *(const bf16x8*)&vbuf[cur][(c * 16 + ln) * 64 + pc];
                        o1[c] = MFMA_BF16(vf, pa1, o1[c], 0, 0, 0);
                        if (f0act) o0[c] = MFMA_BF16(vf, pa0, o0[c], 0, 0, 0);
                    }
                }
        }

        if (i == ntA - 1) { finalize(); initGroup(gB); }
        cur ^= 1;
    }
    finalize();
}

// ---------------------------------------------------------------- launch
extern "C" void kernel_launch(void* const* d_in, const int* in_sizes, int n_in,
                              void* d_out, int out_size, void* d_ws, size_t ws_size,
                              hipStream_t stream) {
    const float* X  = (const float*)d_in[0];
    const float* Wq = (const float*)d_in[1];
    const float* Wk = (const float*)d_in[2];
    const float* Wv = (const float*)d_in[3];
    const float* Wo = (const float*)d_in[4];
    float* out = (float*)d_out;
    char* ws = (char*)d_ws;

    bf16* Xb    = (bf16*)(ws);                    // 16 MB (reused as Attn)
    bf16* WqkT  = (bf16*)(ws + (16u << 20));      //  4 MB [2048][1024]
    bf16* WvT   = (bf16*)(ws + (20u << 20));      //  2 MB
    bf16* WoT   = (bf16*)(ws + (22u << 20));      //  2 MB
    bf16* Qb    = (bf16*)(ws + (24u << 20));      // 16 MB [bh][s][dk] (pre-scaled)
    bf16* Vt    = (bf16*)(ws + (56u << 20));      // 16 MB [bh][dk][s]
    bf16* Attn  = Xb;
    bf16* Kb    = Qb + (size_t)8388608;           // fused-QK second half

    prep_kernel<<<dim3(12288), dim3(256), 0, stream>>>(X, Wq, Wk, Wv, Wo,
                                                       Xb, WqkT, WvT, WoT);

    gemm128<1><<<dim3(1024), dim3(256), 0, stream>>>(Xb, WqkT, Qb);
    gemm128<2><<<dim3(512), dim3(256), 0, stream>>>(Xb, WvT, Vt);

    attn_kernel<<<dim3(512), dim3(256), 0, stream>>>(Qb, Kb, Vt, Attn);

    gemm128<0><<<dim3(512), dim3(256), 0, stream>>>(Attn, WoT, out);
}

// Round 8
// 259.491 us; speedup vs baseline: 1.0493x; 1.0493x over previous
//
#include <hip/hip_runtime.h>

typedef __bf16 bf16;
typedef __attribute__((ext_vector_type(8))) __bf16 bf16x8;
typedef __attribute__((ext_vector_type(4))) float f32x4;
typedef __attribute__((ext_vector_type(4))) unsigned short u16x4;

#define D_MODEL 1024
#define SEQ     2048
#define NB      4
#define NH      16
#define DK      64
#define MROWS   (NB * SEQ)   // 8192

#define MFMA_BF16 __builtin_amdgcn_mfma_f32_16x16x32_bf16
#define EXP2F(x) __builtin_amdgcn_exp2f(x)
#define QSCALE 0.18033688011112042f   // 0.125 * log2(e)

__device__ __forceinline__ bf16 f2b(float f) {
    union { float f; unsigned u; } c; c.f = f;
    unsigned r = (c.u + 0x7fffu + ((c.u >> 16) & 1u)) >> 16;
    union { unsigned short s; bf16 b; } o; o.s = (unsigned short)r;
    return o.b;
}
__device__ __forceinline__ unsigned short f2u(float f) {
    union { float f; unsigned u; } c; c.f = f;
    return (unsigned short)((c.u + 0x7fffu + ((c.u >> 16) & 1u)) >> 16);
}
__device__ __forceinline__ unsigned fbits(float f) {
    union { float f; unsigned u; } c; c.f = f; return c.u;
}
// pack two fp32 -> two bf16 (truncation) in one v_perm_b32
__device__ __forceinline__ unsigned pack2(float lo, float hi) {
    return __builtin_amdgcn_perm(fbits(hi), fbits(lo), 0x07060302u);
}

// ---------------------------------------------------------------- prep (fused)
// blocks [0,8192): X fp32->bf16. blocks [8192,12288): weight transposes into
// WqkvT (3072x1024, rows 0-1023=Wq, 1024-2047=Wk, 2048-3071=Wv) and WoT.
__global__ void prep_kernel(const float* __restrict__ X,
                            const float* __restrict__ Wq, const float* __restrict__ Wk,
                            const float* __restrict__ Wv, const float* __restrict__ Wo,
                            bf16* __restrict__ Xb, bf16* __restrict__ WqkvT,
                            bf16* __restrict__ WoT) {
    __shared__ float tile[32][33];
    const int bid = blockIdx.x;
    if (bid < 8192) {
        int i = bid * 256 + threadIdx.x;
        float4 v = ((const float4*)X)[i];
        u16x4 o; o[0] = f2u(v.x); o[1] = f2u(v.y); o[2] = f2u(v.z); o[3] = f2u(v.w);
        ((u16x4*)Xb)[i] = o;
    } else {
        int r = bid - 8192;
        int w = r >> 10, tl = r & 1023;
        const float* src = (w == 0) ? Wq : (w == 1) ? Wk : (w == 2) ? Wv : Wo;
        bf16* dst = (w == 3) ? WoT : WqkvT + (size_t)w * 1024 * 1024;
        const int n0 = (tl & 31) * 32, k0 = (tl >> 5) * 32;
        const int tx = threadIdx.x & 31, ty = threadIdx.x >> 5;
#pragma unroll
        for (int i = 0; i < 4; i++)
            tile[ty + i * 8][tx] = src[(size_t)(k0 + ty + i * 8) * 1024 + n0 + tx];
        __syncthreads();
#pragma unroll
        for (int i = 0; i < 4; i++)
            dst[(size_t)(n0 + ty + i * 8) * 1024 + k0 + tx] = f2b(tile[tx][ty + i * 8]);
    }
}

// ---------------------------------------------------------------- fused QKV GEMM
// C[8192,3072] = Xb * [Wq;Wk;Wv]^T. 128x128 tile, BK=64, source-side XOR
// swizzle. 1536 blocks, XCD-pinned columns (xcd = bid&7 owns 3 col strips =
// 768 KB of B resident in its L2; X row strips reused 3x in-XCD).
// Cols [0,2048): Q/K -> swapped MFMA orientation (reg<->d), bf16 [proj][bh][s][dk].
// Cols [2048,3072): V -> normal orientation (reg<->s), bf16 [bh][dk][s].
__global__ __launch_bounds__(256) void gemm_qkv(const bf16* __restrict__ A,
                                                const bf16* __restrict__ Bt,
                                                bf16* __restrict__ outQ,
                                                bf16* __restrict__ outV) {
    __shared__ __align__(16) bf16 lA[128 * 64];
    __shared__ __align__(16) bf16 lB[128 * 64];

    const int t = threadIdx.x;
    const int wid = t >> 6, lane = t & 63;
    const int ln = lane & 15, qd = lane >> 4;
    const int wm = wid >> 1, wn = wid & 1;

    const int bid = blockIdx.x;
    const int idx = bid >> 3;
    const int colb = (bid & 7) * 3 + (idx % 3);
    const int rowb = idx / 3;
    const int row0 = rowb * 128, col0 = colb * 128;
    const bool isQK = (col0 < 2048);

    const int srow = t >> 3;
    const int schunk = (t & 7) ^ (srow & 7);
    const bf16* ga = A  + (size_t)(row0 + srow) * 1024 + schunk * 8;
    const bf16* gb = Bt + (size_t)(col0 + srow) * 1024 + schunk * 8;
    const int swk = ln & 7;

    f32x4 acc[4][4];
#pragma unroll
    for (int i = 0; i < 4; i++)
#pragma unroll
        for (int j = 0; j < 4; j++) acc[i][j] = (f32x4){0.f, 0.f, 0.f, 0.f};

    for (int kb = 0; kb < 1024; kb += 64) {
#pragma unroll
        for (int c = 0; c < 4; c++) {
            __builtin_amdgcn_global_load_lds(
                (const __attribute__((address_space(1))) void*)(ga + kb + (size_t)c * 32 * 1024),
                (__attribute__((address_space(3))) void*)(&lA[t * 8 + c * 2048]), 16, 0, 0);
            __builtin_amdgcn_global_load_lds(
                (const __attribute__((address_space(1))) void*)(gb + kb + (size_t)c * 32 * 1024),
                (__attribute__((address_space(3))) void*)(&lB[t * 8 + c * 2048]), 16, 0, 0);
        }
        __syncthreads();

#pragma unroll
        for (int ks = 0; ks < 2; ks++) {
            bf16x8 af[4], bfr[4];
#pragma unroll
            for (int i = 0; i < 4; i++)
                af[i] = *(const bf16x8*)&lA[(wm * 64 + i * 16 + ln) * 64
                                            + ((ks * 4 + qd) ^ swk) * 8];
#pragma unroll
            for (int j = 0; j < 4; j++)
                bfr[j] = *(const bf16x8*)&lB[(wn * 64 + j * 16 + ln) * 64
                                             + ((ks * 4 + qd) ^ swk) * 8];
            if (isQK) {
#pragma unroll
                for (int i = 0; i < 4; i++)
#pragma unroll
                    for (int j = 0; j < 4; j++)
                        acc[i][j] = MFMA_BF16(bfr[j], af[i], acc[i][j], 0, 0, 0);
            } else {
#pragma unroll
                for (int i = 0; i < 4; i++)
#pragma unroll
                    for (int j = 0; j < 4; j++)
                        acc[i][j] = MFMA_BF16(af[i], bfr[j], acc[i][j], 0, 0, 0);
            }
        }
        __syncthreads();
    }

    if (isQK) {
#pragma unroll
        for (int i = 0; i < 4; i++)
#pragma unroll
            for (int j = 0; j < 4; j++) {
                int m  = row0 + wm * 64 + i * 16 + ln;           // s-dim
                int n0 = col0 + wn * 64 + j * 16 + qd * 4;       // proj col
                float scale = (n0 < 1024) ? QSCALE : 1.0f;
                int b = m >> 11, s = m & 2047;
                int h = (n0 & 1023) >> 6, d0 = n0 & 63;
                size_t addr = (((size_t)(b * NH + h) * SEQ + s) * DK + d0)
                              + (size_t)(n0 >> 10) * 8388608;
                u16x4 w;
#pragma unroll
                for (int r = 0; r < 4; r++) w[r] = f2u(acc[i][j][r] * scale);
                *(u16x4*)&outQ[addr] = w;
            }
    } else {
#pragma unroll
        for (int i = 0; i < 4; i++)
#pragma unroll
            for (int j = 0; j < 4; j++) {
                int m0 = row0 + wm * 64 + i * 16 + qd * 4;       // s (consecutive)
                int n  = col0 + wn * 64 + j * 16 + ln - 2048;    // v col
                int b = m0 >> 11, s0 = m0 & 2047;
                int h = n >> 6, d = n & 63;
                size_t addr = ((size_t)(b * NH + h) * DK + d) * SEQ + s0;
                u16x4 w;
#pragma unroll
                for (int r = 0; r < 4; r++) w[r] = f2u(acc[i][j][r]);
                *(u16x4*)&outV[addr] = w;
            }
    }
}

// ---------------------------------------------------------------- output GEMM
// out[8192,1024] fp32 = Attn * Wo^T. Swapped orientation -> f32x4 stores.
// 512 blocks, XCD-pinned columns.
__global__ __launch_bounds__(256) void gemm_o(const bf16* __restrict__ A,
                                              const bf16* __restrict__ Bt,
                                              float* __restrict__ out) {
    __shared__ __align__(16) bf16 lA[128 * 64];
    __shared__ __align__(16) bf16 lB[128 * 64];

    const int t = threadIdx.x;
    const int wid = t >> 6, lane = t & 63;
    const int ln = lane & 15, qd = lane >> 4;
    const int wm = wid >> 1, wn = wid & 1;

    const int bid = blockIdx.x;
    const int colb = bid & 7, rowb = bid >> 3;
    const int row0 = rowb * 128, col0 = colb * 128;

    const int srow = t >> 3;
    const int schunk = (t & 7) ^ (srow & 7);
    const bf16* ga = A  + (size_t)(row0 + srow) * 1024 + schunk * 8;
    const bf16* gb = Bt + (size_t)(col0 + srow) * 1024 + schunk * 8;
    const int swk = ln & 7;

    f32x4 acc[4][4];
#pragma unroll
    for (int i = 0; i < 4; i++)
#pragma unroll
        for (int j = 0; j < 4; j++) acc[i][j] = (f32x4){0.f, 0.f, 0.f, 0.f};

    for (int kb = 0; kb < 1024; kb += 64) {
#pragma unroll
        for (int c = 0; c < 4; c++) {
            __builtin_amdgcn_global_load_lds(
                (const __attribute__((address_space(1))) void*)(ga + kb + (size_t)c * 32 * 1024),
                (__attribute__((address_space(3))) void*)(&lA[t * 8 + c * 2048]), 16, 0, 0);
            __builtin_amdgcn_global_load_lds(
                (const __attribute__((address_space(1))) void*)(gb + kb + (size_t)c * 32 * 1024),
                (__attribute__((address_space(3))) void*)(&lB[t * 8 + c * 2048]), 16, 0, 0);
        }
        __syncthreads();

#pragma unroll
        for (int ks = 0; ks < 2; ks++) {
            bf16x8 af[4], bfr[4];
#pragma unroll
            for (int i = 0; i < 4; i++)
                af[i] = *(const bf16x8*)&lA[(wm * 64 + i * 16 + ln) * 64
                                            + ((ks * 4 + qd) ^ swk) * 8];
#pragma unroll
            for (int j = 0; j < 4; j++)
                bfr[j] = *(const bf16x8*)&lB[(wn * 64 + j * 16 + ln) * 64
                                             + ((ks * 4 + qd) ^ swk) * 8];
#pragma unroll
            for (int i = 0; i < 4; i++)
#pragma unroll
                for (int j = 0; j < 4; j++)
                    acc[i][j] = MFMA_BF16(bfr[j], af[i], acc[i][j], 0, 0, 0);
        }
        __syncthreads();
    }

#pragma unroll
    for (int i = 0; i < 4; i++)
#pragma unroll
        for (int j = 0; j < 4; j++) {
            int m  = row0 + wm * 64 + i * 16 + ln;
            int n0 = col0 + wn * 64 + j * 16 + qd * 4;
            *(f32x4*)&out[(size_t)m * 1024 + n0] = acc[i][j];
        }
}

// ---------------------------------------------------------------- attention
// (R6 kernel — 78 µs known-good.) Block = 4 waves = one bh, one PAIR of
// 64-query groups (gA=p, gB=31-p): exactly 33 uniform 64-key steps. K/V
// double-buffered via global_load_lds (source-side XOR swizzle); fixed-m
// softmax; diagonal mask on single wave-uniform 16x16 block; P v_perm-packed
// into swizzled per-wave LDS; PV in two 32-key halves. 40 KB LDS -> 4 bl/CU.
__global__ __launch_bounds__(256) void attn_kernel(const bf16* __restrict__ Q,
                                                   const bf16* __restrict__ K,
                                                   const bf16* __restrict__ Vt,
                                                   bf16* __restrict__ attn_out) {
    __shared__ __align__(16) bf16 kbuf[2][64 * 64];
    __shared__ __align__(16) bf16 vbuf[2][64 * 64];
    __shared__ __align__(16) bf16 plds[4][16 * 64];

    const int t = threadIdx.x;
    const int wid = t >> 6, lane = t & 63;
    const int ln = lane & 15, qd = lane >> 4;

    const int bid = blockIdx.x;
    const int bh   = ((bid >> 7) << 3) | (bid & 7);   // XCD swizzle
    const int pair = (bid >> 3) & 15;
    const int gA = pair, gB = 31 - pair;
    const int ntA = gA + 1, ntT = 33;

    const bf16* Qh = Q  + (size_t)bh * SEQ * DK;
    const bf16* Kh = K  + (size_t)bh * SEQ * DK;
    const bf16* Vh = Vt + (size_t)bh * DK * SEQ;
    bf16* pw = &plds[wid][0];

    const int srow = t >> 3;
    const int schunk = (t & 7) ^ (srow & 7);
    const bf16* kgp = Kh + (size_t)srow * DK + schunk * 8;
    const bf16* vgp = Vh + (size_t)srow * SEQ + schunk * 8;
    const int swk = ln & 7;

    f32x4 o[4];
    float l;
    int qw0;
    bf16x8 qf0, qf1;

    auto stage = [&](int kb, int buf) {
#pragma unroll
        for (int c = 0; c < 2; c++) {
            __builtin_amdgcn_global_load_lds(
                (const __attribute__((address_space(1))) void*)(kgp + (size_t)(kb + c * 32) * DK),
                (__attribute__((address_space(3))) void*)(&kbuf[buf][t * 8 + c * 2048]), 16, 0, 0);
            __builtin_amdgcn_global_load_lds(
                (const __attribute__((address_space(1))) void*)(vgp + (size_t)c * 32 * SEQ + kb),
                (__attribute__((address_space(3))) void*)(&vbuf[buf][t * 8 + c * 2048]), 16, 0, 0);
        }
    };
    auto initGroup = [&](int g) {
        qw0 = g * 64 + wid * 16;
        qf0 = *(const bf16x8*)(Qh + (size_t)(qw0 + ln) * DK + qd * 8);
        qf1 = *(const bf16x8*)(Qh + (size_t)(qw0 + ln) * DK + 32 + qd * 8);
#pragma unroll
        for (int c = 0; c < 4; c++) o[c] = (f32x4){0.f, 0.f, 0.f, 0.f};
        l = 0.f;
    };
    const int b = bh >> 4, h = bh & 15;
    auto finalize = [&]() {
        float ll = l;
        ll += __shfl_xor(ll, 16);
        ll += __shfl_xor(ll, 32);
        float inv = 1.0f / ll;
        size_t orow = ((size_t)(b * SEQ + qw0 + ln)) * D_MODEL + h * DK;
#pragma unroll
        for (int c = 0; c < 4; c++) {
            u16x4 w;
#pragma unroll
            for (int r = 0; r < 4; r++) w[r] = f2u(o[c][r] * inv);
            *(u16x4*)&attn_out[orow + c * 16 + qd * 4] = w;
        }
    };

    stage(0, 0);
    initGroup(gA);
    int cur = 0;

    for (int i = 0; i < ntT; i++) {
        __syncthreads();
        int nx = i + 1;
        if (nx < ntT) {
            int kbn = ((nx < ntA) ? nx : nx - ntA) * 64;
            stage(kbn, cur ^ 1);
        }
        const int kb = ((i < ntA) ? i : i - ntA) * 64;
        const int nkk = min(4, max(0, ((qw0 + 15 - kb) >> 4) + 1));

        if (nkk > 0) {
            f32x4 st[4];
#pragma unroll
            for (int kk = 0; kk < 4; kk++)
                if (kk < nkk) {
                    const bf16* base = &kbuf[cur][(kk * 16 + ln) * 64];
                    bf16x8 kf0 = *(const bf16x8*)(base + ((qd    ) ^ swk) * 8);
                    bf16x8 kf1 = *(const bf16x8*)(base + ((qd + 4) ^ swk) * 8);
                    f32x4 z = (f32x4){0.f, 0.f, 0.f, 0.f};
                    st[kk] = MFMA_BF16(kf0, qf0, z, 0, 0, 0);
                    st[kk] = MFMA_BF16(kf1, qf1, st[kk], 0, 0, 0);
                }

            float ps = 0.f;
#pragma unroll
            for (int kk = 0; kk < 4; kk++) {
                unsigned pk0 = 0, pk1 = 0;
                if (kk < nkk) {
                    f32x4 s = st[kk];
                    if (kb + kk * 16 == qw0) {
#pragma unroll
                        for (int r = 0; r < 4; r++)
                            if (qd * 4 + r > ln) s[r] = -INFINITY;
                    }
                    float p0 = EXP2F(s[0]);
                    float p1 = EXP2F(s[1]);
                    float p2 = EXP2F(s[2]);
                    float p3 = EXP2F(s[3]);
                    ps += (p0 + p1) + (p2 + p3);
                    pk0 = pack2(p0, p1);
                    pk1 = pack2(p2, p3);
                }
                int cw = 2 * kk + (qd >> 1);
                *(uint2*)&pw[ln * 64 + (cw ^ swk) * 8 + (qd & 1) * 4] =
                    make_uint2(pk0, pk1);
            }
            l += ps;

            asm volatile("s_waitcnt lgkmcnt(0)" ::: "memory");

#pragma unroll
            for (int half = 0; half < 2; half++)
                if (half == 0 || nkk > 2) {
                    bf16x8 pa = *(const bf16x8*)&pw[ln * 64 + ((half * 4 + qd) ^ swk) * 8];
#pragma unroll
                    for (int c = 0; c < 4; c++) {
                        bf16x8 vf = *(const bf16x8*)&vbuf[cur][(c * 16 + ln) * 64
                                        + ((half * 4 + qd) ^ swk) * 8];
                        o[c] = MFMA_BF16(vf, pa, o[c], 0, 0, 0);
                    }
                }
        }

        if (i == ntA - 1) { finalize(); initGroup(gB); }
        cur ^= 1;
    }
    finalize();
}

// ---------------------------------------------------------------- launch
extern "C" void kernel_launch(void* const* d_in, const int* in_sizes, int n_in,
                              void* d_out, int out_size, void* d_ws, size_t ws_size,
                              hipStream_t stream) {
    const float* X  = (const float*)d_in[0];
    const float* Wq = (const float*)d_in[1];
    const float* Wk = (const float*)d_in[2];
    const float* Wv = (const float*)d_in[3];
    const float* Wo = (const float*)d_in[4];
    float* out = (float*)d_out;
    char* ws = (char*)d_ws;

    bf16* Xb    = (bf16*)(ws);                    // 16 MB (reused as Attn)
    bf16* WqkvT = (bf16*)(ws + (16u << 20));      //  6 MB [3072][1024]
    bf16* WoT   = (bf16*)(ws + (22u << 20));      //  2 MB
    bf16* Qb    = (bf16*)(ws + (24u << 20));      // 16 MB [bh][s][dk] (pre-scaled)
    bf16* Vt    = (bf16*)(ws + (56u << 20));      // 16 MB [bh][dk][s]
    bf16* Attn  = Xb;
    bf16* Kb    = Qb + (size_t)8388608;           // fused-QK second half

    prep_kernel<<<dim3(12288), dim3(256), 0, stream>>>(X, Wq, Wk, Wv, Wo,
                                                       Xb, WqkvT, WoT);

    gemm_qkv<<<dim3(1536), dim3(256), 0, stream>>>(Xb, WqkvT, Qb, Vt);

    attn_kernel<<<dim3(1024), dim3(256), 0, stream>>>(Qb, Kb, Vt, Attn);

    gemm_o<<<dim3(512), dim3(256), 0, stream>>>(Attn, WoT, out);
}